// Round 10
// baseline (420.295 us; speedup 1.0000x reference)
//
#include <hip/hip_runtime.h>
#include <hip/hip_bf16.h>

// LSTMFeatureExtractor: 2-layer LSTM (H=64, IN=1, B=2048, T=512) + FC(64->32)+ReLU
// R10: 1024 threads (16 waves, 4 waves/SIMD), grid 256, MB=8.
// Each wave owns 4 units x 4 gates (N=16 cols, col = unit_local*4 + gate):
//   - gate = nq&3 is STATIC per lane -> activation constants need no selects
//   - 6 MFMA/wave (L0 2-chain + L1 4-chain) -> same 432 cy/SIMD floor as R9,
//     but 4-way TLP to hide trans/LDS latency and barrier arrival windows
//     (R9 post-mortem: ~360 cy/iter dead time with only 2 waves/SIMD)
//   - 1 cell/lane (5 act evals, 10 trans instr: per-lane minimum)
//   - gate gather = 4x4 lane transpose: 4 shfl_xor + ~12 selects
// Weights/bias/wx pre-scaled by activation constant (R9 trick kept).

#define HID 64
#define TSTEPS 512
#define MB 8
#define RS 80   // f16 row stride

typedef _Float16 f16x8 __attribute__((ext_vector_type(8)));
typedef float f32x4 __attribute__((ext_vector_type(4)));

#define KSIG (-1.44269504089f)   // -log2(e):  sigma(x) = rcp(1+exp2(KSIG*x))
#define KTANH (2.88539008178f)   // 2*log2(e): tanh(x) = 1-2*rcp(1+exp2(KTANH*x))

__global__ __launch_bounds__(1024, 4) void lstm_feat_kernel(
    const float* __restrict__ x,
    const float* __restrict__ Wih0, const float* __restrict__ Whh0,
    const float* __restrict__ bih0, const float* __restrict__ bhh0,
    const float* __restrict__ Wih1, const float* __restrict__ Whh1,
    const float* __restrict__ bih1, const float* __restrict__ bhh1,
    const float* __restrict__ fcW, const float* __restrict__ fcb,
    float* __restrict__ out)
{
    __shared__ float x_lds[TSTEPS * MB];                   // [t][row], 16 KB
    __shared__ __align__(16) _Float16 h0_lds[2][MB * RS];
    __shared__ __align__(16) _Float16 h1_lds[2][MB * RS];
    __shared__ float h1f32[MB * HID];
    __shared__ float fcw_lds[32 * HID];
    __shared__ float fcb_lds[32];

    const int tid  = threadIdx.x;
    const int wave = tid >> 6;          // 0..15: owns units [4w, 4w+4)
    const int lane = tid & 63;
    const int nq   = lane & 15;
    const int quad = lane >> 4;
    const bool l0q = quad < 2;          // quads 0-1: layer-0 cells; 2-3: layer-1
    const int gate = nq & 3;            // static gate per lane
    const int u    = wave * 4 + (nq >> 2);    // global unit for this lane's col
    const int bbase = blockIdx.x * MB;

    // ---- one-time staging ----
    for (int i = tid; i < TSTEPS * MB; i += 1024) {
        int r = i >> 9, t = i & (TSTEPS - 1);
        x_lds[t * MB + r] = x[(bbase + r) * TSTEPS + t];   // coalesced in t
    }
    for (int i = tid; i < 32 * HID; i += 1024) fcw_lds[i] = fcW[i];
    if (tid < 32) fcb_lds[tid] = fcb[tid];
    for (int i = tid; i < 2 * MB * RS; i += 1024) {
        ((_Float16*)h0_lds)[i] = (_Float16)0.f;            // H0[0]=0 (both bufs)
        ((_Float16*)h1_lds)[i] = (_Float16)0.f;            // H1[0]=0 (both bufs)
    }

    // ---- per-lane weight fragments (B operand), col = unit*4+gate,
    //      pre-scaled by this lane's activation constant ----
    const int nW = gate * 64 + u;                // W row (PyTorch i,f,g,o blocks)
    const float kg = (gate == 2) ? KTANH : KSIG; // g-gate: tanh; i,f,o: sigma
    f16x8 wh0[2], wi1[2], wh1[2];
    #pragma unroll
    for (int ks = 0; ks < 2; ++ks) {
        const int k0 = quad * 8 + ks * 32;
        f16x8 a, b, c;
        #pragma unroll
        for (int j = 0; j < 8; ++j) {
            a[j] = (_Float16)(kg * Whh0[nW * HID + k0 + j]);
            b[j] = (_Float16)(kg * Wih1[nW * HID + k0 + j]);
            c[j] = (_Float16)(kg * Whh1[nW * HID + k0 + j]);
        }
        wh0[ks] = a; wi1[ks] = b; wh1[ks] = c;
    }
    const float b0c = kg * (bih0[nW] + bhh0[nW]);
    const float b1c = kg * (bih1[nW] + bhh1[nW]);
    const float wxc = kg * Wih0[nW];             // IN==1
    const float Ag = (gate == 2) ? -2.f : 1.f;   // act post-form
    const float Bg = (gate == 2) ? 1.f : 0.f;

    const f32x4 bias1 = {b1c, b1c, b1c, b1c};    // loop-invariant L1 C-seed
    const int arow = (nq & 7) * RS + quad * 8;   // A row m = h[batch m&7]
    const int xoff = (quad & 1) * 4;
    // after the 4x4 transpose, this lane owns cell (batch bcell, unit u)
    const int bcell = (quad * 4 + gate) & 7;
    const int waddr = bcell * RS + u;
    const bool tlo = (gate & 1) != 0;            // transpose round-1 side
    const bool thi = (gate & 2) != 0;            // transpose round-2 side
    float cst = 0.f, hl = 0.f;

    __syncthreads();

    // seeds for k=0 (next step's seeds computed in the MFMA shadow)
    f32x4 cA;
    {
        const float4 xv = *(const float4*)&x_lds[0 * MB + xoff];
        cA[0] = fmaf(xv.x, wxc, b0c); cA[1] = fmaf(xv.y, wxc, b0c);
        cA[2] = fmaf(xv.z, wxc, b0c); cA[3] = fmaf(xv.w, wxc, b0c);
    }

    auto step = [&](int xk_next, int pp, bool maskK0) {
        const f16x8 a00 = *(const f16x8*)&h0_lds[pp][arow];
        const f16x8 a01 = *(const f16x8*)&h0_lds[pp][arow + 32];
        const f16x8 a10 = *(const f16x8*)&h1_lds[pp][arow];
        const f16x8 a11 = *(const f16x8*)&h1_lds[pp][arow + 32];

        // L0 2-chain (x+bias seeded), L1 4-chain (bias seeded)
        f32x4 tA = __builtin_amdgcn_mfma_f32_16x16x32_f16(a00, wh0[0], cA, 0, 0, 0);
        f32x4 uA = __builtin_amdgcn_mfma_f32_16x16x32_f16(a00, wi1[0], bias1, 0, 0, 0);
        tA = __builtin_amdgcn_mfma_f32_16x16x32_f16(a01, wh0[1], tA, 0, 0, 0);
        uA = __builtin_amdgcn_mfma_f32_16x16x32_f16(a01, wi1[1], uA, 0, 0, 0);
        uA = __builtin_amdgcn_mfma_f32_16x16x32_f16(a10, wh1[0], uA, 0, 0, 0);
        uA = __builtin_amdgcn_mfma_f32_16x16x32_f16(a11, wh1[1], uA, 0, 0, 0);

        // next-step L0 seeds in the MFMA shadow
        {
            const float4 xv = *(const float4*)&x_lds[xk_next * MB + xoff];
            cA[0] = fmaf(xv.x, wxc, b0c); cA[1] = fmaf(xv.y, wxc, b0c);
            cA[2] = fmaf(xv.z, wxc, b0c); cA[3] = fmaf(xv.w, wxc, b0c);
        }

        const bool docell = maskK0 ? l0q : true;   // only k=0 masks L1 quads
        if (docell) {
            // activation for my gate, 4 batch-elems (pre-scaled args)
            float v0, v1, v2, v3;
            {
                const float p0 = l0q ? tA[0] : uA[0];
                const float p1 = l0q ? tA[1] : uA[1];
                const float p2 = l0q ? tA[2] : uA[2];
                const float p3 = l0q ? tA[3] : uA[3];
                v0 = fmaf(Ag, __builtin_amdgcn_rcpf(1.f + __builtin_amdgcn_exp2f(p0)), Bg);
                v1 = fmaf(Ag, __builtin_amdgcn_rcpf(1.f + __builtin_amdgcn_exp2f(p1)), Bg);
                v2 = fmaf(Ag, __builtin_amdgcn_rcpf(1.f + __builtin_amdgcn_exp2f(p2)), Bg);
                v3 = fmaf(Ag, __builtin_amdgcn_rcpf(1.f + __builtin_amdgcn_exp2f(p3)), Bg);
            }
            // 4x4 transpose across gate lanes: after this, v0..v3 = i,f,g,o
            // of cell (bcell, u).  Round 1: xor 1 over elem-bit0.
            {
                float sa = tlo ? v0 : v1;
                float sb = tlo ? v2 : v3;
                const float ra = __shfl_xor(sa, 1);
                const float rb = __shfl_xor(sb, 1);
                v0 = tlo ? ra : v0;  v1 = tlo ? v1 : ra;
                v2 = tlo ? rb : v2;  v3 = tlo ? v3 : rb;
                sa = thi ? v0 : v2;
                sb = thi ? v1 : v3;
                const float rc = __shfl_xor(sa, 2);
                const float rd = __shfl_xor(sb, 2);
                v0 = thi ? rc : v0;  v2 = thi ? v2 : rc;
                v1 = thi ? rd : v1;  v3 = thi ? v3 : rd;
            }
            // cell update (1 cell/lane): i=v0 f=v1 g=v2 o=v3
            cst = fmaf(v1, cst, v0 * v2);
            const float th = fmaf(-2.f, __builtin_amdgcn_rcpf(
                                 1.f + __builtin_amdgcn_exp2f(KTANH * cst)), 1.f);
            const float h = v3 * th;
            hl = h;
            _Float16* hdst = l0q ? h0_lds[pp ^ 1] : h1_lds[pp ^ 1];
            hdst[waddr] = (_Float16)h;
        }
        __syncthreads();
    };

    // k=0 peeled mask, then branchless; literal parity via manual x2 unroll
    step(1, 0, true);                       // k=0
    for (int k = 1; k < 511; k += 2) {
        step(k + 1, 1, false);              // odd k
        step(k + 2, 0, false);              // even k+1 (k+2 <= 511)
    }
    step(511, 1, false);                    // k=511
    step(511, 0, false);                    // k=512 tail: L1 makes H1[512]

    // ---- epilogue: features = relu(H1[512] @ fcW^T + fcb) ----
    if (!l0q) h1f32[bcell * HID + u] = hl;  // 512 L1 lanes: 8 batches x 64 units
    __syncthreads();

    if (tid < MB * 32) {
        const int o  = tid & 31;
        const int rr = tid >> 5;
        float acc = fcb_lds[o];
        #pragma unroll 8
        for (int kk = 0; kk < HID; ++kk)
            acc += h1f32[rr * HID + kk] * fcw_lds[o * HID + kk];
        out[(bbase + rr) * 32 + o] = fmaxf(acc, 0.f);
    }
}

extern "C" void kernel_launch(void* const* d_in, const int* in_sizes, int n_in,
                              void* d_out, int out_size, void* d_ws, size_t ws_size,
                              hipStream_t stream) {
    const float* x    = (const float*)d_in[0];
    const float* Wih0 = (const float*)d_in[1];
    const float* Whh0 = (const float*)d_in[2];
    const float* bih0 = (const float*)d_in[3];
    const float* bhh0 = (const float*)d_in[4];
    const float* Wih1 = (const float*)d_in[5];
    const float* Whh1 = (const float*)d_in[6];
    const float* bih1 = (const float*)d_in[7];
    const float* bhh1 = (const float*)d_in[8];
    const float* fcW  = (const float*)d_in[9];
    const float* fcb  = (const float*)d_in[10];
    float* out = (float*)d_out;

    lstm_feat_kernel<<<2048 / MB, 1024, 0, stream>>>(
        x, Wih0, Whh0, bih0, bhh0, Wih1, Whh1, bih1, bhh1, fcW, fcb, out);
}

// Round 11
// 386.661 us; speedup vs baseline: 1.0870x; 1.0870x over previous
//
#include <hip/hip_runtime.h>
#include <hip/hip_bf16.h>

// LSTMFeatureExtractor: 2-layer LSTM (H=64, IN=1, B=2048, T=512) + FC(64->32)+ReLU
// R11 = R9 (351 us best: MB=8, 512 thr, layer-split quads, even/odd gate pairs,
// pre-scaled weights, 24 MFMA/SIMD = algebraic minimum, 1 barrier/step) +
//  (a) s_setprio phase bias: prio 1 from barrier-exit through MFMA issue,
//      prio 0 during the trans/cell tail -> waves on one SIMD de-phase so
//      one wave's MFMA window overlaps the other's trans window (R9 showed
//      ~360 cy/iter dead time from phase-locked waves)
//  (b) unified h-row layout [h0(64) | h1(64)] per batch: one A-frag base,
//      4 literal-offset ds_read_b128 (k-chunks 0..3 of the concatenated
//      K=128 row), write offset folded into a single loop-invariant address.

#define HID 64
#define TSTEPS 512
#define MB 8
#define RS 136  // f16 per combined h-row: [h0:64 | h1:64] + 8 pad (272B stride)

typedef _Float16 f16x8 __attribute__((ext_vector_type(8)));
typedef float f32x4 __attribute__((ext_vector_type(4)));
typedef float f32x2 __attribute__((ext_vector_type(2)));

#define KSIG (-1.44269504089f)   // -log2(e):  sigma(x) = rcp(1+exp2(KSIG*x))
#define KTANH (2.88539008178f)   // 2*log2(e): tanh(x) = 1-2*rcp(1+exp2(KTANH*x))

__global__ __launch_bounds__(512, 2) void lstm_feat_kernel(
    const float* __restrict__ x,
    const float* __restrict__ Wih0, const float* __restrict__ Whh0,
    const float* __restrict__ bih0, const float* __restrict__ bhh0,
    const float* __restrict__ Wih1, const float* __restrict__ Whh1,
    const float* __restrict__ bih1, const float* __restrict__ bhh1,
    const float* __restrict__ fcW, const float* __restrict__ fcb,
    float* __restrict__ out)
{
    __shared__ float x_lds[TSTEPS * MB];                   // [t][row], 16 KB
    __shared__ __align__(16) _Float16 h_lds[2][MB * RS];   // [buf][batch][h0|h1]
    __shared__ float h1f32[MB * HID];
    __shared__ float fcw_lds[32 * HID];
    __shared__ float fcb_lds[32];

    const int tid  = threadIdx.x;
    const int wave = tid >> 6;      // 0..7: owns units [8w, 8w+8)
    const int lane = tid & 63;
    const int nq   = lane & 15;
    const int quad = lane >> 4;
    const bool l0q = quad < 2;          // quads 0-1: layer-0 cells; 2-3: layer-1
    const bool evn = (nq & 1) == 0;     // even lanes: {i,g}; odd: {f,o}
    const int ucell = wave * 8 + (nq >> 1);   // unit this lane-pair owns
    const int bbase = blockIdx.x * MB;

    // ---- one-time staging ----
    for (int i = tid; i < TSTEPS * MB; i += 512) {
        int r = i >> 9, t = i & (TSTEPS - 1);
        x_lds[t * MB + r] = x[(bbase + r) * TSTEPS + t];   // coalesced in t
    }
    for (int i = tid; i < 32 * HID; i += 512) fcw_lds[i] = fcW[i];
    if (tid < 32) fcb_lds[tid] = fcb[tid];
    for (int i = tid; i < 2 * MB * RS; i += 512)
        ((_Float16*)h_lds)[i] = (_Float16)0.f;             // H0[0]=H1[0]=0

    // ---- per-lane weight fragments (B operand), gate-interleaved cols,
    //      pre-scaled by this lane's activation constants ----
    const int nA = (nq & 1) * 64 + ucell;        // W row for gate i or f (sigma)
    const int nB = (2 + (nq & 1)) * 64 + ucell;  // W row for gate g or o
    const float kBs = evn ? KTANH : KSIG;        // tileB: g lanes tanh, o lanes sigma
    f16x8 wA0[2], wB0[2], wiA[2], whA[2], wiB[2], whB[2];
    #pragma unroll
    for (int ks = 0; ks < 2; ++ks) {
        const int k0 = quad * 8 + ks * 32;
        f16x8 a, b, c, d, e, f;
        #pragma unroll
        for (int j = 0; j < 8; ++j) {
            a[j] = (_Float16)(KSIG * Whh0[nA * HID + k0 + j]);
            b[j] = (_Float16)(kBs  * Whh0[nB * HID + k0 + j]);
            c[j] = (_Float16)(KSIG * Wih1[nA * HID + k0 + j]);
            d[j] = (_Float16)(KSIG * Whh1[nA * HID + k0 + j]);
            e[j] = (_Float16)(kBs  * Wih1[nB * HID + k0 + j]);
            f[j] = (_Float16)(kBs  * Whh1[nB * HID + k0 + j]);
        }
        wA0[ks] = a; wB0[ks] = b; wiA[ks] = c; whA[ks] = d; wiB[ks] = e; whB[ks] = f;
    }
    const float bA0 = KSIG * (bih0[nA] + bhh0[nA]);
    const float bB0 = kBs  * (bih0[nB] + bhh0[nB]);
    const float bA1 = KSIG * (bih1[nA] + bhh1[nA]);
    const float bB1 = kBs  * (bih1[nB] + bhh1[nB]);
    const float wxA = KSIG * Wih0[nA];           // IN==1
    const float wxB = kBs  * Wih0[nB];

    const float AB = evn ? -2.f : 1.f;           // tileB post-form
    const float BB = evn ? 1.f : 0.f;

    const f32x4 biasA1 = {bA1, bA1, bA1, bA1};   // loop-invariant L1 C-seeds
    const f32x4 biasB1 = {bB1, bB1, bB1, bB1};
    // A-frag base: row m = batch (nq&7), k-slice quad*8 within the combined
    // 128-wide row; chunks at +0 (h0 k0), +32 (h0 k1), +64 (h1 k0), +96 (h1 k1)
    const int arow = (nq & 7) * RS + quad * 8;
    const int xoff = (quad & 1) * 4;

    // this lane's 2 cells: batches b0,b0+1 of its layer; layer offset 0 or 64
    const int e0 = evn ? 0 : 2;
    const int b0 = (quad * 4 + e0) & 7;
    const int waddr = b0 * RS + (l0q ? 0 : 64) + ucell;
    f32x2 cst2 = {0.f, 0.f};
    float hl0 = 0.f, hl1 = 0.f;

    __syncthreads();

    // k=0 seeds (next step's seeds computed in the MFMA shadow)
    f32x4 cA, cB;
    {
        const float4 xv = *(const float4*)&x_lds[0 * MB + xoff];
        cA[0] = fmaf(xv.x, wxA, bA0); cA[1] = fmaf(xv.y, wxA, bA0);
        cA[2] = fmaf(xv.z, wxA, bA0); cA[3] = fmaf(xv.w, wxA, bA0);
        cB[0] = fmaf(xv.x, wxB, bB0); cB[1] = fmaf(xv.y, wxB, bB0);
        cB[2] = fmaf(xv.z, wxB, bB0); cB[3] = fmaf(xv.w, wxB, bB0);
    }

    auto step = [&](int xk_next, int pp, bool maskK0) {
        // ---- high priority: the barrier-exit critical chain (LDS reads ->
        //      MFMA issue). A wave here outranks a wave in its trans tail. ----
        __builtin_amdgcn_s_setprio(1);
        const _Float16* hsrc = h_lds[pp];
        const f16x8 a00 = *(const f16x8*)&hsrc[arow];        // h0 k-chunk 0
        const f16x8 a01 = *(const f16x8*)&hsrc[arow + 32];   // h0 k-chunk 1
        const f16x8 a10 = *(const f16x8*)&hsrc[arow + 64];   // h1 k-chunk 0
        const f16x8 a11 = *(const f16x8*)&hsrc[arow + 96];   // h1 k-chunk 1

        // L0: two 2-chains (x+bias seeded); L1: two 4-chains (bias seeded)
        f32x4 tA = __builtin_amdgcn_mfma_f32_16x16x32_f16(a00, wA0[0], cA, 0, 0, 0);
        f32x4 tB = __builtin_amdgcn_mfma_f32_16x16x32_f16(a00, wB0[0], cB, 0, 0, 0);
        f32x4 uA = __builtin_amdgcn_mfma_f32_16x16x32_f16(a00, wiA[0], biasA1, 0, 0, 0);
        f32x4 uB = __builtin_amdgcn_mfma_f32_16x16x32_f16(a00, wiB[0], biasB1, 0, 0, 0);
        tA = __builtin_amdgcn_mfma_f32_16x16x32_f16(a01, wA0[1], tA, 0, 0, 0);
        tB = __builtin_amdgcn_mfma_f32_16x16x32_f16(a01, wB0[1], tB, 0, 0, 0);
        uA = __builtin_amdgcn_mfma_f32_16x16x32_f16(a01, wiA[1], uA, 0, 0, 0);
        uB = __builtin_amdgcn_mfma_f32_16x16x32_f16(a01, wiB[1], uB, 0, 0, 0);
        uA = __builtin_amdgcn_mfma_f32_16x16x32_f16(a10, whA[0], uA, 0, 0, 0);
        uB = __builtin_amdgcn_mfma_f32_16x16x32_f16(a10, whB[0], uB, 0, 0, 0);
        uA = __builtin_amdgcn_mfma_f32_16x16x32_f16(a11, whA[1], uA, 0, 0, 0);
        uB = __builtin_amdgcn_mfma_f32_16x16x32_f16(a11, whB[1], uB, 0, 0, 0);

        // next-step seeds in the MFMA shadow (independent of MFMA results)
        {
            const float4 xv = *(const float4*)&x_lds[xk_next * MB + xoff];
            cA[0] = fmaf(xv.x, wxA, bA0); cA[1] = fmaf(xv.y, wxA, bA0);
            cA[2] = fmaf(xv.z, wxA, bA0); cA[3] = fmaf(xv.w, wxA, bA0);
            cB[0] = fmaf(xv.x, wxB, bB0); cB[1] = fmaf(xv.y, wxB, bB0);
            cB[2] = fmaf(xv.z, wxB, bB0); cB[3] = fmaf(xv.w, wxB, bB0);
        }
        // ---- low priority: trans/cell tail (yield issue to MFMA-phase waves)
        __builtin_amdgcn_s_setprio(0);

        const bool docell = maskK0 ? l0q : true;   // only k=0 masks L1 quads
        if (docell) {
            float sA[4], sB[4];
            #pragma unroll
            for (int r = 0; r < 4; ++r) {
                const float pA = l0q ? tA[r] : uA[r];    // pre-scaled args
                const float pB = l0q ? tB[r] : uB[r];
                sA[r] = __builtin_amdgcn_rcpf(1.f + __builtin_amdgcn_exp2f(pA));
                sB[r] = fmaf(AB, __builtin_amdgcn_rcpf(1.f + __builtin_amdgcn_exp2f(pB)), BB);
            }
            const float rxA0 = __shfl_xor(evn ? sA[2] : sA[0], 1);
            const float rxA1 = __shfl_xor(evn ? sA[3] : sA[1], 1);
            const float rxB0 = __shfl_xor(evn ? sB[2] : sB[0], 1);
            const float rxB1 = __shfl_xor(evn ? sB[3] : sB[1], 1);
            f32x2 iv2, fv2, gv2, ov2;
            iv2.x = evn ? sA[0] : rxA0;  iv2.y = evn ? sA[1] : rxA1;
            fv2.x = evn ? rxA0 : sA[2];  fv2.y = evn ? rxA1 : sA[3];
            gv2.x = evn ? sB[0] : rxB0;  gv2.y = evn ? sB[1] : rxB1;
            ov2.x = evn ? rxB0 : sB[2];  ov2.y = evn ? rxB1 : sB[3];
            cst2 = fv2 * cst2 + iv2 * gv2;           // v_pk_fma pair
            f32x2 ex, rc;
            ex.x = __builtin_amdgcn_exp2f(KTANH * cst2.x);
            ex.y = __builtin_amdgcn_exp2f(KTANH * cst2.y);
            rc.x = __builtin_amdgcn_rcpf(1.f + ex.x);
            rc.y = __builtin_amdgcn_rcpf(1.f + ex.y);
            const f32x2 th = 1.f - 2.f * rc;         // v_pk_fma
            const f32x2 h2 = ov2 * th;               // v_pk_mul
            hl0 = h2.x; hl1 = h2.y;
            _Float16* hdst = h_lds[pp ^ 1];
            hdst[waddr]      = (_Float16)h2.x;
            hdst[waddr + RS] = (_Float16)h2.y;
        }
        __syncthreads();
    };

    // k=0 peeled mask, then branchless; literal parity via manual x2 unroll
    step(1, 0, true);                       // k=0
    for (int k = 1; k < 511; k += 2) {
        step(k + 1, 1, false);              // odd k
        step(k + 2, 0, false);              // even k+1 (k+2 <= 511)
    }
    step(511, 1, false);                    // k=511
    step(511, 0, false);                    // k=512 tail: L1 makes H1[512]

    // ---- epilogue: features = relu(H1[512] @ fcW^T + fcb) ----
    if (!l0q) {
        h1f32[b0 * HID + ucell]       = hl0;
        h1f32[(b0 + 1) * HID + ucell] = hl1;
    }
    __syncthreads();

    if (tid < MB * 32) {
        const int o  = tid & 31;
        const int rr = tid >> 5;
        float acc = fcb_lds[o];
        #pragma unroll 8
        for (int kk = 0; kk < HID; ++kk)
            acc += h1f32[rr * HID + kk] * fcw_lds[o * HID + kk];
        out[(bbase + rr) * 32 + o] = fmaxf(acc, 0.f);
    }
}

extern "C" void kernel_launch(void* const* d_in, const int* in_sizes, int n_in,
                              void* d_out, int out_size, void* d_ws, size_t ws_size,
                              hipStream_t stream) {
    const float* x    = (const float*)d_in[0];
    const float* Wih0 = (const float*)d_in[1];
    const float* Whh0 = (const float*)d_in[2];
    const float* bih0 = (const float*)d_in[3];
    const float* bhh0 = (const float*)d_in[4];
    const float* Wih1 = (const float*)d_in[5];
    const float* Whh1 = (const float*)d_in[6];
    const float* bih1 = (const float*)d_in[7];
    const float* bhh1 = (const float*)d_in[8];
    const float* fcW  = (const float*)d_in[9];
    const float* fcb  = (const float*)d_in[10];
    float* out = (float*)d_out;

    lstm_feat_kernel<<<2048 / MB, 512, 0, stream>>>(
        x, Wih0, Whh0, bih0, bhh0, Wih1, Whh1, bih1, bhh1, fcW, fcb, out);
}